// Round 1
// baseline (1766.643 us; speedup 1.0000x reference)
//
#include <hip/hip_runtime.h>
#include <math.h>

#define BB 32
#define TT 24
#define NN 256
#define FF 16
#define HH 128
#define G4 512  // 4*H

typedef _Float16 half8 __attribute__((ext_vector_type(8)));
typedef float f32x4 __attribute__((ext_vector_type(4)));

__device__ __forceinline__ float sigf(float x) { return 1.f / (1.f + __expf(-x)); }
__device__ __forceinline__ float tanhfast(float x) { return 1.f - 2.f / (__expf(2.f * x) + 1.f); }

// fp32 -> (hi, lo) fp16 split: v ~= hi + lo, residual ~2^-22 relative.
__device__ __forceinline__ void split8(const float* v, half8& hi, half8& lo) {
#pragma unroll
  for (int i = 0; i < 8; ++i) {
    const _Float16 h = (_Float16)v[i];
    hi[i] = h;
    lo[i] = (_Float16)(v[i] - (float)h);
  }
}

// ---------------------------------------------------------------------------
// K0a: pre-split+swizzle gcn_W into B-frag tiles.
// Wfrag[kc(5)][ct(32)][lane][8]: element W_op[k][n]:
//   kc<4 : gcnW[16 + kc*32 + k][ct*16 + n]   (h part, rows 16..143)
//   kc==4: k<16 ? gcnW[k][ct*16+n] : 0       (x part zero-padded to K=32)
// with k = (lane>>4)*8 + j, n = lane&15.
// ---------------------------------------------------------------------------
__global__ __launch_bounds__(64) void k0_wswz(const float* __restrict__ gcnW,
                                              _Float16* __restrict__ WfH,
                                              _Float16* __restrict__ WfL) {
  const int bid = blockIdx.x;  // kc*32 + ct, 0..159
  const int kc = bid >> 5, ct = bid & 31;
  const int l = threadIdx.x, quad = l >> 4, lo16 = l & 15;
  float v[8];
#pragma unroll
  for (int j = 0; j < 8; ++j) {
    const int k = quad * 8 + j;
    float val = 0.f;
    if (kc < 4) val = gcnW[(size_t)(16 + kc * 32 + k) * G4 + ct * 16 + lo16];
    else if (k < 16) val = gcnW[(size_t)k * G4 + ct * 16 + lo16];
    v[j] = val;
  }
  half8 hi, lo;
  split8(v, hi, lo);
  const size_t off = (size_t)bid * 512 + l * 8;
  *(half8*)&WfH[off] = hi;
  *(half8*)&WfL[off] = lo;
}

// ---------------------------------------------------------------------------
// K0b: pre-split+swizzle adjacency (adj[:, T-1]) into A-frag tiles.
// Afrag[b][nt16(16)][kc(8)][lane][8]: element adj[b][T-1][m][k],
//   m = nt16*16 + (lane&15), k = kc*32 + (lane>>4)*8 + j.
// ---------------------------------------------------------------------------
__global__ __launch_bounds__(64) void k0_aswz(const float* __restrict__ adj,
                                              _Float16* __restrict__ AfH,
                                              _Float16* __restrict__ AfL) {
  const int nt16 = blockIdx.x >> 3, kc = blockIdx.x & 7;
  const int b = blockIdx.y;
  const int l = threadIdx.x, quad = l >> 4, lo16 = l & 15;
  const float* src =
      adj + (((size_t)(b * TT + TT - 1)) * NN + nt16 * 16 + lo16) * NN + kc * 32 + quad * 8;
  const float4 v0 = *(const float4*)src;
  const float4 v1 = *(const float4*)(src + 4);
  float v[8] = {v0.x, v0.y, v0.z, v0.w, v1.x, v1.y, v1.z, v1.w};
  half8 hi, lo;
  split8(v, hi, lo);
  const size_t off = (((size_t)b * 16 + nt16) * 8 + kc) * 512 + l * 8;
  *(half8*)&AfH[off] = hi;
  *(half8*)&AfL[off] = lo;
}

// ---------------------------------------------------------------------------
// K1: Ax[b,t,n,f] = sum_j A[b,n,j] * x[b,t,j,f]   (fp32, parallel over b,t)
// ---------------------------------------------------------------------------
__global__ __launch_bounds__(256) void k1_ax(const float* __restrict__ adj,
                                             const float* __restrict__ x,
                                             float* __restrict__ Ax) {
  const int bt = blockIdx.x;
  const int b = bt / TT;
  const float* Abase = adj + ((size_t)(b * TT + (TT - 1)) * NN) * NN;
  const float* xbase = x + (size_t)bt * NN * FF;

  __shared__ float x_s[NN * FF];
  __shared__ float A_s[64 * 65];

  for (int i4 = threadIdx.x; i4 < (NN * FF) / 4; i4 += 256) {
    ((float4*)x_s)[i4] = ((const float4*)xbase)[i4];
  }
  const int rg = threadIdx.x >> 2;
  const int fg = threadIdx.x & 3;

  for (int rt = 0; rt < 4; ++rt) {
    float4 acc = make_float4(0.f, 0.f, 0.f, 0.f);
    for (int jc = 0; jc < 4; ++jc) {
      __syncthreads();
      for (int i = threadIdx.x; i < 64 * 64; i += 256) {
        const int r = i >> 6, j = i & 63;
        A_s[r * 65 + j] = Abase[(size_t)(rt * 64 + r) * NN + jc * 64 + j];
      }
      __syncthreads();
#pragma unroll 8
      for (int j = 0; j < 64; ++j) {
        const float a = A_s[rg * 65 + j];
        const float4 xv = *(const float4*)&x_s[(jc * 64 + j) * FF + fg * 4];
        acc.x += a * xv.x;
        acc.y += a * xv.y;
        acc.z += a * xv.z;
        acc.w += a * xv.w;
      }
    }
    *(float4*)&Ax[((size_t)bt * NN + rt * 64 + rg) * FF + fg * 4] = acc;
  }
}

// ---------------------------------------------------------------------------
// K2 fused: all TT timesteps in one persistent kernel.
// Grid 256 = 8 nt x 32 b, 256 threads, 1 block/CU. Cooperative launch for
// co-residency; per-b 8-block barrier (monotonic counter, agent scope).
// XCD swizzle: blocks of the same b share an XCD (id&7 == b>>2), so the
// h-frag exchange + barrier stay in one L2.
// Per step:
//   phase A: Ah(32x128) = A(32x256)@h(256x128), A-frags from LDS, h from glb.
//   phase B: gates(32x512) = [Ah|Ax|0](32x160) @ Wfrag; wave w owns column
//     tiles tl = 8*(cc>>1) + 2w + (cc&1) so each lane holds i,f,g,o of one
//     hidden column -> LSTM pointwise entirely in registers (c-state in regs).
//   epilogue: h -> LDS (layout swap) -> split fp16 frag pair -> global,
//     then per-b barrier. Last step: write h32 only, no frags/barrier.
// LDS: region 32x164 (20.5K) + h_s 32x130 (16.3K) + A-frags 2x16K = 70.4 KB.
// ---------------------------------------------------------------------------
__global__ __launch_bounds__(256, 1) void k2_fused(
    const _Float16* __restrict__ AfH, const _Float16* __restrict__ AfL,
    const _Float16* __restrict__ WfH, const _Float16* __restrict__ WfL,
    const float* __restrict__ Ax, const float* __restrict__ gcnb,
    _Float16* __restrict__ hfH0, _Float16* __restrict__ hfL0,
    _Float16* __restrict__ hfH1, _Float16* __restrict__ hfL1,
    float* __restrict__ h32, unsigned int* __restrict__ bar) {
  const int id = blockIdx.x;
  const int j = id >> 3;
  const int b = (id & 7) * 4 + (j >> 3);  // same-b blocks -> same XCD (id%8)
  const int nt = j & 7;
  const int n0 = nt * 32;
  const int tid = threadIdx.x;
  const int w = tid >> 6, l = tid & 63, quad = l >> 4, lo16 = l & 15;

  __shared__ float region[32 * 164];      // Ah (0..127) | Ax (128..143) | 0
  __shared__ float h_s[32 * 130];
  __shared__ _Float16 AsH[16 * 512];      // 2 rt x 8 kc tiles
  __shared__ _Float16 AsL[16 * 512];

  // ---- one-time: A-frags -> LDS, zero-pad region cols 144..159 ----
  {
    const size_t abase = (((size_t)b * 16 + 2 * nt) * 8) * 512;
    for (int i = tid; i < 1024; i += 256) {
      *(half8*)&AsH[i * 8] = *(const half8*)&AfH[abase + (size_t)i * 8];
      *(half8*)&AsL[i * 8] = *(const half8*)&AfL[abase + (size_t)i * 8];
    }
    const int r = tid >> 3, f = (tid & 7) * 2;
    *(float2*)&region[r * 164 + 144 + f] = make_float2(0.f, 0.f);
  }

  // bias registers: lane covers hidden cols (2w+cw)*16+lo16, gates 0..3
  float bi[2][4];
#pragma unroll
  for (int cw = 0; cw < 2; ++cw)
#pragma unroll
    for (int g = 0; g < 4; ++g) bi[cw][g] = gcnb[g * HH + (2 * w + cw) * 16 + lo16];

  float c_r[16];  // [rt][cw][r] — LSTM cell state lives in registers
#pragma unroll
  for (int i = 0; i < 16; ++i) c_r[i] = 0.f;

  unsigned int* barb = bar + b * 16;  // 64B-padded per-b counter

  __syncthreads();  // AsH/AsL + pad visible

  for (int t = 0; t < TT; ++t) {
    const _Float16* hiH = (t & 1) ? hfH1 : hfH0;
    const _Float16* hiL = (t & 1) ? hfL1 : hfL0;
    _Float16* hoH = (t & 1) ? hfH0 : hfH1;
    _Float16* hoL = (t & 1) ? hfL0 : hfL1;

    // stage Ax[t] -> region cols 128..143
    {
      const int r = tid >> 3, f = (tid & 7) * 2;
      const float2 v = *(const float2*)&Ax[(((size_t)(b * TT + t)) * NN + n0 + r) * FF + f];
      *(float2*)&region[r * 164 + 128 + f] = v;
    }

    // ---- phase A: wave w -> hcol tiles {2w, 2w+1}, row tiles {0,1} ----
    f32x4 accA[2][2];
#pragma unroll
    for (int rt = 0; rt < 2; ++rt)
#pragma unroll
      for (int cc = 0; cc < 2; ++cc) accA[rt][cc] = (f32x4){0.f, 0.f, 0.f, 0.f};

    for (int kc = 0; kc < 8; ++kc) {
      half8 aH[2], aL[2], bH[2], bL[2];
#pragma unroll
      for (int rt = 0; rt < 2; ++rt) {
        aH[rt] = *(const half8*)&AsH[(rt * 8 + kc) * 512 + l * 8];
        aL[rt] = *(const half8*)&AsL[(rt * 8 + kc) * 512 + l * 8];
      }
#pragma unroll
      for (int cc = 0; cc < 2; ++cc) {
        const size_t off = (((size_t)b * 8 + kc) * 8 + (w * 2 + cc)) * 512 + l * 8;
        bH[cc] = *(const half8*)&hiH[off];
        bL[cc] = *(const half8*)&hiL[off];
      }
#pragma unroll
      for (int rt = 0; rt < 2; ++rt)
#pragma unroll
        for (int cc = 0; cc < 2; ++cc) {
          accA[rt][cc] = __builtin_amdgcn_mfma_f32_16x16x32_f16(aL[rt], bH[cc], accA[rt][cc], 0, 0, 0);
          accA[rt][cc] = __builtin_amdgcn_mfma_f32_16x16x32_f16(aH[rt], bL[cc], accA[rt][cc], 0, 0, 0);
          accA[rt][cc] = __builtin_amdgcn_mfma_f32_16x16x32_f16(aH[rt], bH[cc], accA[rt][cc], 0, 0, 0);
        }
    }
    // C-write Ah (col=lane&15, row=quad*4+reg) into region cols 0..127
#pragma unroll
    for (int rt = 0; rt < 2; ++rt)
#pragma unroll
      for (int cc = 0; cc < 2; ++cc)
#pragma unroll
        for (int r = 0; r < 4; ++r)
          region[(rt * 16 + quad * 4 + r) * 164 + (w * 2 + cc) * 16 + lo16] = accA[rt][cc][r];
    __syncthreads();  // B1: Ah + Ax staged

    // ---- phase B: wave w -> col tiles tl = 8*(cc>>1)+2w+(cc&1) ----
    f32x4 acc[2][8];
#pragma unroll
    for (int rt = 0; rt < 2; ++rt)
#pragma unroll
      for (int cc = 0; cc < 8; ++cc) acc[rt][cc] = (f32x4){0.f, 0.f, 0.f, 0.f};

    for (int kc = 0; kc < 5; ++kc) {
      half8 pH[2], pL[2];
#pragma unroll
      for (int rt = 0; rt < 2; ++rt) {
        const float* src = &region[(rt * 16 + lo16) * 164 + kc * 32 + quad * 8];
        const float4 v0 = *(const float4*)src;
        const float4 v1 = *(const float4*)(src + 4);
        float av[8] = {v0.x, v0.y, v0.z, v0.w, v1.x, v1.y, v1.z, v1.w};
        split8(av, pH[rt], pL[rt]);
      }
#pragma unroll
      for (int cc = 0; cc < 8; ++cc) {
        const int tl = 8 * (cc >> 1) + 2 * w + (cc & 1);
        const size_t woff = ((size_t)(kc * 32 + tl)) * 512 + l * 8;
        const half8 wH = *(const half8*)&WfH[woff];
        const half8 wL = *(const half8*)&WfL[woff];
#pragma unroll
        for (int rt = 0; rt < 2; ++rt) {
          acc[rt][cc] = __builtin_amdgcn_mfma_f32_16x16x32_f16(pL[rt], wH, acc[rt][cc], 0, 0, 0);
          acc[rt][cc] = __builtin_amdgcn_mfma_f32_16x16x32_f16(pH[rt], wL, acc[rt][cc], 0, 0, 0);
          acc[rt][cc] = __builtin_amdgcn_mfma_f32_16x16x32_f16(pH[rt], wH, acc[rt][cc], 0, 0, 0);
        }
      }
    }
    __syncthreads();  // B2: region reads done (next step may overwrite)

    // ---- LSTM pointwise, fully in registers on C layout ----
    // lane: node = rt*16+quad*4+r, col = (2w+cw)*16+lo16
    // i = acc[rt][0+cw], f = acc[rt][2+cw], g = acc[rt][4+cw], o = acc[rt][6+cw]
#pragma unroll
    for (int rt = 0; rt < 2; ++rt)
#pragma unroll
      for (int cw = 0; cw < 2; ++cw)
#pragma unroll
        for (int r = 0; r < 4; ++r) {
          const float iv = sigf(acc[rt][0 + cw][r] + bi[cw][0]);
          const float fv = sigf(acc[rt][2 + cw][r] + bi[cw][1]);
          const float gv = tanhfast(acc[rt][4 + cw][r] + bi[cw][2]);
          const float ov = sigf(acc[rt][6 + cw][r] + bi[cw][3]);
          const int ci = rt * 8 + cw * 4 + r;
          const float cnew = fv * c_r[ci] + iv * gv;
          c_r[ci] = cnew;
          const float hv = ov * tanhfast(cnew);
          const int node = rt * 16 + quad * 4 + r;
          const int col = (2 * w + cw) * 16 + lo16;
          h_s[node * 130 + col] = hv;
          if (t == TT - 1 && nt == 0)
            h32[((size_t)b * 32 + node) * HH + col] = hv;
        }

    if (t != TT - 1) {
      __syncthreads();  // B3: h_s ready
      // hfrag production: wave w -> hcol tiles {2w,2w+1}; this block = k-chunk nt
#pragma unroll
      for (int cc = 0; cc < 2; ++cc) {
        const int ct = w * 2 + cc;
        float v[8];
#pragma unroll
        for (int jj = 0; jj < 8; ++jj) v[jj] = h_s[(quad * 8 + jj) * 130 + ct * 16 + lo16];
        half8 hh, hl;
        split8(v, hh, hl);
        const size_t off = (((size_t)b * 8 + nt) * 8 + ct) * 512 + l * 8;
        *(half8*)&hoH[off] = hh;
        *(half8*)&hoL[off] = hl;
      }
      // ---- per-b inter-block barrier (8 blocks, same XCD) ----
      __threadfence();   // release: flush hOut stores to coherent point
      __syncthreads();   // all threads of block flushed
      if (tid == 0) {
        __hip_atomic_fetch_add(barb, 1u, __ATOMIC_RELEASE, __HIP_MEMORY_SCOPE_AGENT);
        const unsigned int tgt = 8u * (unsigned)(t + 1);
        while (__hip_atomic_load(barb, __ATOMIC_ACQUIRE, __HIP_MEMORY_SCOPE_AGENT) < tgt) {
          __builtin_amdgcn_s_sleep(1);
        }
      }
      __syncthreads();
      __threadfence();   // acquire: invalidate stale hIn lines before reads
    }
  }
}

// ---------------------------------------------------------------------------
// Tail: GRU over t + fc5/fc2/fc3/fc4. grid = B, 384 threads.
// h32 layout: [b][node 0..31][128] (only node tile 0 is stored; tsi=5 < 32).
// ---------------------------------------------------------------------------
__global__ __launch_bounds__(384) void k_tail(
    const float* __restrict__ x, const float* __restrict__ h32,
    const int* __restrict__ tsi_p, const float* __restrict__ gruWih,
    const float* __restrict__ gruWhh, const float* __restrict__ gru_bih,
    const float* __restrict__ gru_bhh, const float* __restrict__ fc2W,
    const float* __restrict__ fc2b, const float* __restrict__ fc3W,
    const float* __restrict__ fc3b, const float* __restrict__ fc4W,
    const float* __restrict__ fc4b, const float* __restrict__ fc5W,
    const float* __restrict__ fc5b, float* __restrict__ out) {
  const int b = blockIdx.x;
  const int m = threadIdx.x;
  const int tsi = tsi_p[0];

  __shared__ float h_s[HH];
  __shared__ float xts[TT * FF];
  __shared__ float sum_s[384];
  __shared__ float gh_s[384];
  __shared__ float hc_s[2 * HH];
  __shared__ float xr_s[HH];
  __shared__ float f2_s[HH];
  __shared__ float f3_s[64];

  float4 whh[32];
#pragma unroll
  for (int q = 0; q < 32; ++q) whh[q] = *(const float4*)&gruWhh[(size_t)m * HH + q * 4];
  float4 wih[4];
#pragma unroll
  for (int q = 0; q < 4; ++q) wih[q] = *(const float4*)&gruWih[(size_t)m * FF + q * 4];
  const float bih_r = gru_bih[m];
  const float bhh_r = gru_bhh[m];

  {
    const int t = m >> 4, f = m & 15;
    xts[m] = x[(((size_t)b * TT + t) * NN + tsi) * FF + f];
  }
  if (m < HH) h_s[m] = 0.f;
  __syncthreads();

  for (int t = 0; t < TT; ++t) {
    float gi = bih_r;
#pragma unroll
    for (int q = 0; q < 4; ++q) {
      const float4 xv = *(const float4*)&xts[t * FF + q * 4];
      gi += wih[q].x * xv.x + wih[q].y * xv.y + wih[q].z * xv.z + wih[q].w * xv.w;
    }
    float gh = bhh_r;
#pragma unroll
    for (int q = 0; q < 32; ++q) {
      const float4 hv = *(const float4*)&h_s[q * 4];
      gh += whh[q].x * hv.x + whh[q].y * hv.y + whh[q].z * hv.z + whh[q].w * hv.w;
    }
    sum_s[m] = gi + gh;
    gh_s[m] = gh;
    __syncthreads();
    float hnew = 0.f;
    if (m < HH) {
      const float r = sigf(sum_s[m]);
      const float z = sigf(sum_s[HH + m]);
      const float ghn = gh_s[2 * HH + m];
      const float nn = tanhfast(sum_s[2 * HH + m] - ghn + r * ghn);
      hnew = (1.f - z) * nn + z * h_s[m];
    }
    __syncthreads();
    if (m < HH) h_s[m] = hnew;
    __syncthreads();
  }

  if (m < HH) {
    hc_s[m] = h_s[m];
    xr_s[m] = fmaxf(h32[((size_t)b * 32 + tsi) * HH + m], 0.f);
  }
  __syncthreads();
  if (m < HH) {
    float v = fc5b[m];
    const float* wr = fc5W + (size_t)m * HH;
#pragma unroll 8
    for (int k = 0; k < HH; k += 4) {
      const float4 wv = *(const float4*)(wr + k);
      v += xr_s[k] * wv.x + xr_s[k + 1] * wv.y + xr_s[k + 2] * wv.z + xr_s[k + 3] * wv.w;
    }
    hc_s[HH + m] = v;
  }
  __syncthreads();
  if (m < HH) {
    float v = fc2b[m];
    const float* wr = fc2W + (size_t)m * 2 * HH;
#pragma unroll 8
    for (int k = 0; k < 2 * HH; k += 4) {
      const float4 wv = *(const float4*)(wr + k);
      v += hc_s[k] * wv.x + hc_s[k + 1] * wv.y + hc_s[k + 2] * wv.z + hc_s[k + 3] * wv.w;
    }
    f2_s[m] = fmaxf(v, 0.f);
  }
  __syncthreads();
  if (m < 64) {
    float v = fc3b[m];
    const float* wr = fc3W + (size_t)m * HH;
#pragma unroll 8
    for (int k = 0; k < HH; k += 4) {
      const float4 wv = *(const float4*)(wr + k);
      v += f2_s[k] * wv.x + f2_s[k + 1] * wv.y + f2_s[k + 2] * wv.z + f2_s[k + 3] * wv.w;
    }
    f3_s[m] = fmaxf(v, 0.f);
  }
  __syncthreads();
  if (m < 24) {
    float v = fc4b[m];
    const float* wr = fc4W + (size_t)m * 64;
#pragma unroll
    for (int k = 0; k < 64; k += 4) {
      const float4 wv = *(const float4*)(wr + k);
      v += f3_s[k] * wv.x + f3_s[k + 1] * wv.y + f3_s[k + 2] * wv.z + f3_s[k + 3] * wv.w;
    }
    out[b * 24 + m] = v;
  }
}

// ---------------------------------------------------------------------------
extern "C" void kernel_launch(void* const* d_in, const int* in_sizes, int n_in,
                              void* d_out, int out_size, void* d_ws, size_t ws_size,
                              hipStream_t stream) {
  const float* x = (const float*)d_in[0];
  const float* adj = (const float*)d_in[1];
  const int* tsi = (const int*)d_in[2];
  const float* gcnW = (const float*)d_in[3];
  const float* gcnb = (const float*)d_in[4];
  const float* gruWih = (const float*)d_in[5];
  const float* gruWhh = (const float*)d_in[6];
  const float* gru_bih = (const float*)d_in[7];
  const float* gru_bhh = (const float*)d_in[8];
  const float* fc2W = (const float*)d_in[9];
  const float* fc2b = (const float*)d_in[10];
  const float* fc3W = (const float*)d_in[11];
  const float* fc3b = (const float*)d_in[12];
  const float* fc4W = (const float*)d_in[13];
  const float* fc4b = (const float*)d_in[14];
  const float* fc5W = (const float*)d_in[15];
  const float* fc5b = (const float*)d_in[16];
  float* out = (float*)d_out;

  // ws layout (elements)
  float* Ax = (float*)d_ws;                           // 32*24*256*16 = 3,145,728 f
  _Float16* hfH0 = (_Float16*)(Ax + 3145728);         // 1,048,576 h
  _Float16* hfL0 = hfH0 + 1048576;                    // 1,048,576 h
  unsigned int* bar = (unsigned int*)(hfL0 + 1048576);// 512 u32 (32 b x 16 pad)
  _Float16* hfH1 = (_Float16*)(bar + 512);            // 1,048,576 h
  _Float16* hfL1 = hfH1 + 1048576;                    // 1,048,576 h
  float* h32 = (float*)(hfL1 + 1048576);              // 32*32*128 = 131,072 f
  _Float16* AfH = (_Float16*)(h32 + 131072);          // 32*16*8*512 = 2,097,152 h
  _Float16* AfL = AfH + 2097152;                      // 2,097,152 h
  _Float16* WfH = AfL + 2097152;                      // 5*32*512 = 81,920 h
  _Float16* WfL = WfH + 81920;                        // 81,920 h

  // zero: hfH0/hfL0 (h(-1)=0) + bar (step counters) — contiguous, one memset
  hipMemsetAsync(hfH0, 0, 1048576 * 2 * 2 + 512 * 4, stream);

  k0_wswz<<<dim3(160), 64, 0, stream>>>(gcnW, WfH, WfL);
  k0_aswz<<<dim3(128, BB), 64, 0, stream>>>(adj, AfH, AfL);
  k1_ax<<<dim3(BB * TT), 256, 0, stream>>>(adj, x, Ax);

  // persistent fused scan: cooperative launch guarantees all 256 blocks
  // co-resident (1 block/CU, LDS 70.4KB); per-b barriers inside.
  {
    void* kargs[12];
    kargs[0] = (void*)&AfH;
    kargs[1] = (void*)&AfL;
    kargs[2] = (void*)&WfH;
    kargs[3] = (void*)&WfL;
    kargs[4] = (void*)&Ax;
    kargs[5] = (void*)&gcnb;
    kargs[6] = (void*)&hfH0;
    kargs[7] = (void*)&hfL0;
    kargs[8] = (void*)&hfH1;
    kargs[9] = (void*)&hfL1;
    kargs[10] = (void*)&h32;
    kargs[11] = (void*)&bar;
    hipLaunchCooperativeKernel((void*)k2_fused, dim3(256), dim3(256), kargs, 0, stream);
  }

  k_tail<<<dim3(BB), 384, 0, stream>>>(x, h32, tsi, gruWih, gruWhh, gru_bih, gru_bhh, fc2W,
                                       fc2b, fc3W, fc3b, fc4W, fc4b, fc5W, fc5b, out);
}